// Round 6
// baseline (276.682 us; speedup 1.0000x reference)
//
#include <hip/hip_runtime.h>

#define BB 8
#define TT 2048
#define DD 128
#define CH 32              // 64-row k-chunks; grid = CH*BB = 256 blocks = 256 CUs

typedef __attribute__((ext_vector_type(8))) short bf16x8;
typedef __attribute__((ext_vector_type(4))) float f32x4;
typedef unsigned short u16;
typedef unsigned int u32;

static __device__ __forceinline__ float bf2f(u16 u) {
    union { unsigned int i; float f; } v; v.i = ((unsigned int)u) << 16; return v.f;
}
static __device__ __forceinline__ u16 f2bf(float f) {
    union { float f; unsigned int i; } v; v.f = f;
    unsigned int x = v.i;
    return (u16)((x + 0x7FFFu + ((x >> 16) & 1u)) >> 16);  // RNE
}

// ===========================================================================
// ONE cooperative kernel, 256 blocks x 1024 threads, 82 KB LDS (=> 1 block/CU,
// so cooperative launch guarantees all 256 blocks co-resident).
//
// R5 post-mortem: the 256MiB ws poison-fill (~45us) is timed EVERY iteration
// whether or not we use ws -> workspace is free. The R3-R5 redundant-Gram
// (32x LDS restaging) has a ~40us floor. So: go back to the R1 3-phase
// pipeline (each phase ~1-3us of real work, full-GPU) but replace the two
// ~10us kernel boundaries with two ~1us per-batch atomic barriers (32 blocks
// each, device-scope fence + acquire spin; visibility mechanism validated by
// R2's correct-but-slow grid.sync version).
//
// Phase 1: block (b, c) computes partial Gram P[c][b] = enc_chunk^T @ enc_chunk
//          (64 rows, K=64) via swizzled LDS transpose + 16x16x32 MFMA.
// Phase 2: after per-batch barrier, block reduces its 1/32 share of G[b]
//          (elementwise over 32 chunks, fp32 accum -> bf16) -> G in ws.
// Phase 3: after second barrier, stage G[b] -> LDS and apply 64 dec rows
//          (R4/R5 harness-verified frag-keyed read + epilogue).
// Counters zeroed by a 64B hipMemsetAsync before the kernel (same stream).
// ===========================================================================
__global__ __launch_bounds__(1024, 4) void luong_fused(const float* __restrict__ enc,
                                                       const float* __restrict__ dec,
                                                       u16* __restrict__ P,
                                                       u16* __restrict__ G,
                                                       u32* __restrict__ cnt,
                                                       float* __restrict__ out) {
    const int bid  = blockIdx.x;           // 0..255
    const int b    = bid & 7;              // XCD-local batch (same-b blocks share L2)
    const int c    = bid >> 3;             // k-chunk (phase 1) and q-chunk (phase 3)
    const int t    = threadIdx.x;
    const int wave = t >> 6, lane = t & 63, quad = lane >> 4, ln = lane & 15;

    __shared__ __align__(16) u16 Gt[DD * 64];     // 16 KB swizzled enc^T chunk
    __shared__ __align__(16) u16 Gs[DD * DD];     // 32 KB frag-keyed G
    __shared__ __align__(16) u16 occPad[17408];   // 34 KB pad -> 82 KB total -> 1 blk/CU
    if (dec == nullptr) occPad[t] = 0;            // keep pad live (never true)

    // ---- dec loads first (HBM latency hides under phases 1-2) -> A-frags ----
    const int rowt = wave & 3, dgrp = wave >> 2;
    const float* drow = dec + ((size_t)b * TT + (size_t)c * 64 + rowt * 16 + ln) * DD
                        + quad * 8;
    bf16x8 dfrag[4];
    #pragma unroll
    for (int ks = 0; ks < 4; ++ks) {
        const float4 d0 = *(const float4*)(drow + ks * 32);
        const float4 d1 = *(const float4*)(drow + ks * 32 + 4);
        union { u16 o[8]; bf16x8 v; } u;
        u.o[0] = f2bf(d0.x); u.o[1] = f2bf(d0.y); u.o[2] = f2bf(d0.z); u.o[3] = f2bf(d0.w);
        u.o[4] = f2bf(d1.x); u.o[5] = f2bf(d1.y); u.o[6] = f2bf(d1.z); u.o[7] = f2bf(d1.w);
        dfrag[ks] = u.v;
    }

    // ---- Phase 1: stage enc chunk transposed+swizzled, Gram MFMA ----
    const int d = t & 127, kg = t >> 7;    // column d, k-granule kg (8 k's each)
    {
        const float* src = enc + ((size_t)b * TT + (size_t)c * 64) * DD;
        union { u16 o[8]; uint4 q; } cv;
        #pragma unroll
        for (int i = 0; i < 8; ++i) cv.o[i] = f2bf(src[(kg * 8 + i) * DD + d]);
        *(uint4*)&Gt[d * 64 + ((kg ^ (d & 7)) << 3)] = cv.q;
    }
    __syncthreads();

    // 16 waves x 4 tiles: wave (mt = w>>1, parity = w&1) -> tiles (mt, parity+2s).
    const int mt = wave >> 1, parity = wave & 1;
    f32x4 acc[4];
    #pragma unroll
    for (int s = 0; s < 4; ++s) acc[s] = (f32x4){0.f, 0.f, 0.f, 0.f};

    #pragma unroll
    for (int ks = 0; ks < 2; ++ks) {
        const int g = ((ks * 4 + quad) ^ (ln & 7)) << 3;   // swizzled k-granule
        const bf16x8 af = *(const bf16x8*)&Gt[(mt * 16 + ln) * 64 + g];
        #pragma unroll
        for (int s = 0; s < 4; ++s) {
            const int nt = parity + 2 * s;
            const bf16x8 bf = *(const bf16x8*)&Gt[(nt * 16 + ln) * 64 + g];
            acc[s] = __builtin_amdgcn_mfma_f32_16x16x32_bf16(af, bf, acc[s], 0, 0, 0);
        }
    }

    // P[c][b], frag-keyed: elem (row,col) of tile (i,j) at (i*8+j)*256 + col*16 + row.
    {
        u16* Pb = P + ((size_t)c * BB + b) * (DD * DD);
        #pragma unroll
        for (int s = 0; s < 4; ++s) {
            const int nt = parity + 2 * s;
            u16 o[4];
            #pragma unroll
            for (int r = 0; r < 4; ++r) o[r] = f2bf(acc[s][r]);
            *(ushort4*)&Pb[(mt * 8 + nt) * 256 + ln * 16 + quad * 4] = *(const ushort4*)o;
        }
    }

    // ---- Barrier 1: all 32 blocks of batch b finished writing P[*][b] ----
    __threadfence();                       // device-scope release of P
    __syncthreads();
    if (t == 0) {
        __hip_atomic_fetch_add(&cnt[b], 1u, __ATOMIC_ACQ_REL, __HIP_MEMORY_SCOPE_AGENT);
        while (__hip_atomic_load(&cnt[b], __ATOMIC_ACQUIRE, __HIP_MEMORY_SCOPE_AGENT)
               < (u32)CH) {
            __builtin_amdgcn_s_sleep(2);
        }
    }
    __syncthreads();

    // ---- Phase 2: reduce our 1/32 share of G[b] (128 ushort4) ----
    if (t < 128) {
        const int e = c * 128 + t;         // ushort4 index within batch, 0..4095
        const ushort4* Pu = (const ushort4*)P;
        float sx = 0.f, sy = 0.f, sz = 0.f, sw = 0.f;
        #pragma unroll
        for (int c2 = 0; c2 < CH; ++c2) {
            const ushort4 v = Pu[((size_t)c2 * BB + b) * 4096 + e];
            sx += bf2f(v.x); sy += bf2f(v.y); sz += bf2f(v.z); sw += bf2f(v.w);
        }
        ushort4 o; o.x = f2bf(sx); o.y = f2bf(sy); o.z = f2bf(sz); o.w = f2bf(sw);
        ((ushort4*)G)[(size_t)b * 4096 + e] = o;
    }

    // ---- Barrier 2: G[b] complete ----
    __threadfence();                       // device-scope release of G
    __syncthreads();
    if (t == 0) {
        __hip_atomic_fetch_add(&cnt[8 + b], 1u, __ATOMIC_ACQ_REL, __HIP_MEMORY_SCOPE_AGENT);
        while (__hip_atomic_load(&cnt[8 + b], __ATOMIC_ACQUIRE, __HIP_MEMORY_SCOPE_AGENT)
               < (u32)CH) {
            __builtin_amdgcn_s_sleep(2);
        }
    }
    __syncthreads();

    // ---- Phase 3: stage G[b] -> Gs, then apply (R4/R5 harness-verified) ----
    {
        const uint4* Gq = (const uint4*)(G + (size_t)b * DD * DD);
        #pragma unroll
        for (int i = 0; i < 2; ++i)
            ((uint4*)Gs)[i * 1024 + t] = Gq[i * 1024 + t];
    }
    __syncthreads();

    f32x4 oacc[2];
    #pragma unroll
    for (int dtl = 0; dtl < 2; ++dtl) oacc[dtl] = (f32x4){0.f, 0.f, 0.f, 0.f};

    #pragma unroll
    for (int ks = 0; ks < 4; ++ks) {
        const int mtk  = ks * 2 + (quad >> 1);
        const int boff = ln * 16 + (quad & 1) * 8;
        #pragma unroll
        for (int dtl = 0; dtl < 2; ++dtl) {
            const int dt = dgrp * 2 + dtl;
            const bf16x8 bbf = *(const bf16x8*)&Gs[(mtk * 8 + dt) * 256 + boff];
            oacc[dtl] = __builtin_amdgcn_mfma_f32_16x16x32_bf16(
                dfrag[ks], bbf, oacc[dtl], 0, 0, 0);
        }
    }

    // Epilogue: C/D layout col=lane&15, row=quad*4+reg (HW-verified).
    float* ob = out + ((size_t)b * TT + (size_t)c * 64 + rowt * 16) * DD;
    #pragma unroll
    for (int dtl = 0; dtl < 2; ++dtl) {
        const int dcol = (dgrp * 2 + dtl) * 16 + ln;
        #pragma unroll
        for (int r = 0; r < 4; ++r)
            ob[(quad * 4 + r) * DD + dcol] = oacc[dtl][r];
    }
}

extern "C" void kernel_launch(void* const* d_in, const int* in_sizes, int n_in,
                              void* d_out, int out_size, void* d_ws, size_t ws_size,
                              hipStream_t stream) {
    const float* enc = (const float*)d_in[0];  // (8,2048,128) fp32
    const float* dec = (const float*)d_in[1];  // (8,2048,128) fp32
    float* out = (float*)d_out;                // (8,2048,128) fp32

    // ws layout: P bf16 partials (CH*BB*128*128*2 = 8 MB) | G bf16 (256 KB) | counters
    char* ws = (char*)d_ws;
    u16* P  = (u16*)ws;
    u16* G  = (u16*)(ws + (size_t)CH * BB * DD * DD * sizeof(u16));
    u32* cnt = (u32*)(ws + (size_t)CH * BB * DD * DD * sizeof(u16)
                         + (size_t)BB * DD * DD * sizeof(u16));

    hipMemsetAsync(cnt, 0, 16 * sizeof(u32), stream);   // zero barrier counters

    void* args[] = {(void*)&enc, (void*)&dec, (void*)&P, (void*)&G,
                    (void*)&cnt, (void*)&out};
    hipLaunchCooperativeKernel((void*)luong_fused, dim3(CH * BB), dim3(1024),
                               args, 0, stream);
}

// Round 7
// 80.175 us; speedup vs baseline: 3.4510x; 3.4510x over previous
//
#include <hip/hip_runtime.h>

#define BB 8
#define TT 2048
#define DD 128
#define CH 32              // 64-row k-chunks; gram grid = CH*BB = 256 blocks

typedef __attribute__((ext_vector_type(8))) short bf16x8;
typedef __attribute__((ext_vector_type(4))) float f32x4;
typedef unsigned short u16;

static __device__ __forceinline__ float bf2f(u16 u) {
    union { unsigned int i; float f; } v; v.i = ((unsigned int)u) << 16; return v.f;
}
static __device__ __forceinline__ u16 f2bf(float f) {
    union { float f; unsigned int i; } v; v.f = f;
    unsigned int x = v.i;
    return (u16)((x + 0x7FFFu + ((x >> 16) & 1u)) >> 16);  // RNE
}

// ===========================================================================
// R7: back to the 3-kernel pipeline (launch-boundary sync is the CHEAPEST
// cross-block barrier on this chip: R2 grid.sync ~50us/barrier, R6 atomic
// spin ~95us/barrier, kernel boundary ~3-5us). Each kernel is the fastest
// harness-VERIFIED version of its phase:
//   K1 = R6 phase 1 (1024 thr, swizzled staging, 0 bank conflicts in R6 PMC)
//   K2 = R1 reduce  (verbatim)
//   K3 = R6 phase 3 (1024 thr, frag-keyed Gs, reg-held dec A-frags)
// ===========================================================================

// ---------------------------------------------------------------------------
// K1: partial Gram P[c][b] = enc_chunk^T @ enc_chunk (64 rows, K=64).
// P frag-keyed: elem (row,col) of tile (i,j) at (i*8+j)*256 + col*16 + row.
// ---------------------------------------------------------------------------
__global__ __launch_bounds__(1024, 4) void gram_mfma(const float* __restrict__ enc,
                                                     u16* __restrict__ P) {
    const int bid  = blockIdx.x;           // 0..255
    const int b    = bid & 7;
    const int c    = bid >> 3;             // k-chunk 0..31
    const int t    = threadIdx.x;
    const int wave = t >> 6, lane = t & 63, quad = lane >> 4, ln = lane & 15;

    __shared__ __align__(16) u16 Gt[DD * 64];     // 16 KB swizzled enc^T chunk

    // Stage: thread (d = t&127, kg = t>>7) converts 8 k's of column d,
    // writes one swizzled 16B granule (R6-verified, conflict-free).
    const int d = t & 127, kg = t >> 7;
    {
        const float* src = enc + ((size_t)b * TT + (size_t)c * 64) * DD;
        union { u16 o[8]; uint4 q; } cv;
        #pragma unroll
        for (int i = 0; i < 8; ++i) cv.o[i] = f2bf(src[(kg * 8 + i) * DD + d]);
        *(uint4*)&Gt[d * 64 + ((kg ^ (d & 7)) << 3)] = cv.q;
    }
    __syncthreads();

    // 16 waves x 4 tiles: wave (mt = w>>1, parity = w&1) -> tiles (mt, parity+2s).
    const int mt = wave >> 1, parity = wave & 1;
    f32x4 acc[4];
    #pragma unroll
    for (int s = 0; s < 4; ++s) acc[s] = (f32x4){0.f, 0.f, 0.f, 0.f};

    #pragma unroll
    for (int ks = 0; ks < 2; ++ks) {
        const int g = ((ks * 4 + quad) ^ (ln & 7)) << 3;   // swizzled k-granule
        const bf16x8 af = *(const bf16x8*)&Gt[(mt * 16 + ln) * 64 + g];
        #pragma unroll
        for (int s = 0; s < 4; ++s) {
            const int nt = parity + 2 * s;
            const bf16x8 bf = *(const bf16x8*)&Gt[(nt * 16 + ln) * 64 + g];
            acc[s] = __builtin_amdgcn_mfma_f32_16x16x32_bf16(af, bf, acc[s], 0, 0, 0);
        }
    }

    u16* Pb = P + ((size_t)c * BB + b) * (DD * DD);
    #pragma unroll
    for (int s = 0; s < 4; ++s) {
        const int nt = parity + 2 * s;
        u16 o[4];
        #pragma unroll
        for (int r = 0; r < 4; ++r) o[r] = f2bf(acc[s][r]);
        *(ushort4*)&Pb[(mt * 8 + nt) * 256 + ln * 16 + quad * 4] = *(const ushort4*)o;
    }
}

// ---------------------------------------------------------------------------
// K2: G[b] = sum_c P[c][b], elementwise fp32 accum -> bf16 (R1 verbatim).
// ---------------------------------------------------------------------------
__global__ __launch_bounds__(128) void gram_reduce(const u16* __restrict__ P,
                                                   u16* __restrict__ G) {
    const int g = blockIdx.x * 128 + threadIdx.x;   // 0..32767
    const ushort4* Pu = (const ushort4*)P;
    const int stride = BB * DD * DD / 4;
    float sx = 0.f, sy = 0.f, sz = 0.f, sw = 0.f;
    #pragma unroll
    for (int c = 0; c < CH; ++c) {
        const ushort4 v = Pu[(size_t)c * stride + g];
        sx += bf2f(v.x); sy += bf2f(v.y); sz += bf2f(v.z); sw += bf2f(v.w);
    }
    ushort4 o; o.x = f2bf(sx); o.y = f2bf(sy); o.z = f2bf(sz); o.w = f2bf(sw);
    ((ushort4*)G)[g] = o;
}

// ---------------------------------------------------------------------------
// K3: out[b,chunk] = dec_chunk @ G[b] (R6 phase-3 verbatim).
// ---------------------------------------------------------------------------
__global__ __launch_bounds__(1024, 4) void apply_mfma(const float* __restrict__ dec,
                                                      const u16* __restrict__ G,
                                                      float* __restrict__ out) {
    const int bid  = blockIdx.x;           // 0..255
    const int b    = bid & 7;
    const int c    = bid >> 3;             // q-chunk 0..31
    const int t    = threadIdx.x;
    const int wave = t >> 6, lane = t & 63, quad = lane >> 4, ln = lane & 15;

    __shared__ __align__(16) u16 Gs[DD * DD];     // 32 KB frag-keyed G

    // dec loads first (HBM latency hides under Gs staging) -> A-frags.
    const int rowt = wave & 3, dgrp = wave >> 2;
    const float* drow = dec + ((size_t)b * TT + (size_t)c * 64 + rowt * 16 + ln) * DD
                        + quad * 8;
    bf16x8 dfrag[4];
    #pragma unroll
    for (int ks = 0; ks < 4; ++ks) {
        const float4 d0 = *(const float4*)(drow + ks * 32);
        const float4 d1 = *(const float4*)(drow + ks * 32 + 4);
        union { u16 o[8]; bf16x8 v; } u;
        u.o[0] = f2bf(d0.x); u.o[1] = f2bf(d0.y); u.o[2] = f2bf(d0.z); u.o[3] = f2bf(d0.w);
        u.o[4] = f2bf(d1.x); u.o[5] = f2bf(d1.y); u.o[6] = f2bf(d1.z); u.o[7] = f2bf(d1.w);
        dfrag[ks] = u.v;
    }

    // Stage G[b] (frag-keyed, raw copy), 2 x uint4 per thread = 32 KB.
    {
        const uint4* Gq = (const uint4*)(G + (size_t)b * DD * DD);
        #pragma unroll
        for (int i = 0; i < 2; ++i)
            ((uint4*)Gs)[i * 1024 + t] = Gq[i * 1024 + t];
    }
    __syncthreads();

    f32x4 oacc[2];
    #pragma unroll
    for (int dtl = 0; dtl < 2; ++dtl) oacc[dtl] = (f32x4){0.f, 0.f, 0.f, 0.f};

    #pragma unroll
    for (int ks = 0; ks < 4; ++ks) {
        const int mtk  = ks * 2 + (quad >> 1);
        const int boff = ln * 16 + (quad & 1) * 8;
        #pragma unroll
        for (int dtl = 0; dtl < 2; ++dtl) {
            const int dt = dgrp * 2 + dtl;
            const bf16x8 bbf = *(const bf16x8*)&Gs[(mtk * 8 + dt) * 256 + boff];
            oacc[dtl] = __builtin_amdgcn_mfma_f32_16x16x32_bf16(
                dfrag[ks], bbf, oacc[dtl], 0, 0, 0);
        }
    }

    // Epilogue: C/D layout col=lane&15, row=quad*4+reg (HW-verified).
    float* ob = out + ((size_t)b * TT + (size_t)c * 64 + rowt * 16) * DD;
    #pragma unroll
    for (int dtl = 0; dtl < 2; ++dtl) {
        const int dcol = (dgrp * 2 + dtl) * 16 + ln;
        #pragma unroll
        for (int r = 0; r < 4; ++r)
            ob[(quad * 4 + r) * DD + dcol] = oacc[dtl][r];
    }
}

extern "C" void kernel_launch(void* const* d_in, const int* in_sizes, int n_in,
                              void* d_out, int out_size, void* d_ws, size_t ws_size,
                              hipStream_t stream) {
    const float* enc = (const float*)d_in[0];  // (8,2048,128) fp32
    const float* dec = (const float*)d_in[1];  // (8,2048,128) fp32
    float* out = (float*)d_out;                // (8,2048,128) fp32

    // ws: P bf16 partials (CH*BB*128*128*2 = 8 MB) | G bf16 (256 KB)
    u16* P = (u16*)d_ws;
    u16* G = (u16*)((char*)d_ws + (size_t)CH * BB * DD * DD * sizeof(u16));

    gram_mfma<<<dim3(CH * BB), 1024, 0, stream>>>(enc, P);
    gram_reduce<<<BB * DD * DD / 4 / 128, 128, 0, stream>>>(P, G);
    apply_mfma<<<dim3(CH * BB), 1024, 0, stream>>>(dec, G, out);
}